// Round 5
// baseline (185.568 us; speedup 1.0000x reference)
//
#include <hip/hip_runtime.h>
#include <hip/hip_bf16.h>
#include <stdint.h>

// Problem constants
#define BATCH 64
#define CH 3
#define HW 224
#define PP 7
#define GHW 32           // 32x32 patches
#define PD 147           // 7*7*3
#define DIM 1024
#define NTOK 65536       // 64 * 1024 tokens

typedef int   i32x4 __attribute__((ext_vector_type(4)));
typedef float f32x4v __attribute__((ext_vector_type(4)));

// ---------------- positional embedding table pe2[32][512] ----------------
// pe2[g][c] = sin(g*omega[c])        for c<256
//           = cos(g*omega[c-256])    for c>=256
// Output col<512  (quads 0/1, x-based): pe = pe2[xg][col]   with xg = token%32
// Output col>=512 (quads 2/3, y-based): pe = pe2[yg][col-512] with yg = gh
__global__ void pe_gen(float* __restrict__ pe2) {
    int id = blockIdx.x * 256 + threadIdx.x;      // < 16384 = 32*512
    int g = id >> 9, c = id & 511;
    int k = c & 255;
    float omega = exp2f(-13.287712379549449f * (float)k * (1.0f / 255.0f));
    float arg = (float)g * omega;
    pe2[id] = (c < 256) ? sinf(arg) : cosf(arg);
}

// ---------------- mean|W| partial sums (deterministic) ----------------
__global__ void wabs(const float* __restrict__ W, float* __restrict__ part) {
    __shared__ float red[256];
    int t = threadIdx.x;
    int base = blockIdx.x * 1024;                 // 147 blocks * 1024 = 150528
    float s = fabsf(W[base + t]) + fabsf(W[base + t + 256]) +
              fabsf(W[base + t + 512]) + fabsf(W[base + t + 768]);
    red[t] = s;
    __syncthreads();
    for (int off = 128; off > 0; off >>= 1) {
        if (t < off) red[t] += red[t + off];
        __syncthreads();
    }
    if (t == 0) part[blockIdx.x] = red[0];
}

// ---------------- ternary weight quant -> int8, MFMA B layout ----------------
// Wq layout: [c = k>>4 (12)][d(1024)][j = k&15] int8, k padded to 192. 192 KB total.
__global__ void wquant(const float* __restrict__ W, const float* __restrict__ part,
                       float* __restrict__ swbuf, signed char* __restrict__ Wq) {
    __shared__ float red[256];
    int tid = threadIdx.x;
    red[tid] = (tid < 147) ? part[tid] : 0.f;
    __syncthreads();
    for (int off = 128; off > 0; off >>= 1) {
        if (tid < off) red[tid] += red[tid + off];
        __syncthreads();
    }
    float m = fmaxf(red[0] * (1.0f / 150528.0f), 1e-5f);
    float sw = 1.0f / m;
    if (blockIdx.x == 0 && tid == 0) swbuf[0] = m;   // dequant scale for gemm

    int e = blockIdx.x * 256 + tid;               // < 196608 = 1024*192
    int d = e / 192, k = e % 192;
    float t = 0.f;
    if (k < 147) {
        t = rintf(W[d * 147 + k] * sw);
        t = fminf(fmaxf(t, -1.f), 1.f);
    }
    Wq[(((k >> 4) << 10) | d) * 16 + (k & 15)] = (signed char)(int)t;
}

// ---------------- fused patchify + LN1 + int8 quant + i8 GEMM + LN2 + posemb ----------
// grid: 2048 blocks, XCD-swizzled gh-major. Block = 32 tokens x 1024 cols.
// 512 threads = 8 waves (2 wm x 4 wn); wave tile 16 rows x 256 cols (2 halves x 8 frags).
// B is NOT staged: fragments load directly from L2-resident Wq (192 KB/XCD).
// Register discipline (unified VGPR+AGPR budget 128 @ launch_bounds(512,4)):
//   acc 64 (AGPR) + 32 transient bf + ~20 misc. kk-loop rolled + sched_barrier(0)
//   between halves so the compiler cannot hoist all 48 B loads.
// LDS (26624 B):
//   xs   [0,     18816) : x-stage, [c(3)][p1(7)][224] f32
//   A8   [18816, 25472) : quantized A int8, [row(32)][k(208)]  (k padded 192->208 for banks)
//   stats[25472, 26496) : [rloc(32)][wn(4)][{sum,sq}] f32
//   sxl  [26496, 26624) : per-token dequant scale f32
__global__ __launch_bounds__(512, 4) void fused(
    const float* __restrict__ x, const float* __restrict__ g1,
    const float* __restrict__ b1, const signed char* __restrict__ Wq,
    const float* __restrict__ swbuf, const float* __restrict__ bproj,
    const float* __restrict__ g2, const float* __restrict__ b2,
    const float* __restrict__ pe2, float* __restrict__ out) {
    extern __shared__ char lds[];
    float*        xs    = (float*)lds;
    uint32_t*     A8w   = (uint32_t*)(lds + 18816);
    const i32x4*  A4    = (const i32x4*)(lds + 18816);
    float*        stats = (float*)(lds + 25472);
    float*        sxl   = (float*)(lds + 26496);

    int tid = threadIdx.x;
    int wave = tid >> 6, lane = tid & 63;
    int wm = wave >> 2, wn = wave & 3;
    int l15 = lane & 15, lg = lane >> 4;

    // XCD-swizzled, gh-major mapping: XCD x owns logical blocks [x*256, x*256+256)
    int lblk = (blockIdx.x & 7) * 256 + (blockIdx.x >> 3);
    int gh = lblk >> 6, b = lblk & 63;
    int rowbase = b * 1024 + gh * 32;             // output token base

    // ---- phase 0: coalesced x stage (3 ch x 7 rows x 224 floats, as float4) ----
    const f32x4v* x4 = (const f32x4v*)x;
    int base4 = b * 37632 + gh * 392;             // (b*150528 + gh*7*224)/4
    f32x4v* xs4 = (f32x4v*)xs;
#pragma unroll
    for (int it = 0; it < 3; it++) {
        int j = tid + it * 512;
        if (j < 1176) {
            int c = j / 392, i4 = j - c * 392;
            xs4[j] = x4[base4 + c * 12544 + i4];
        }
    }
    __syncthreads();

    // ---- phase 1: LN1 + per-token absmax int8 fake-quant -> A8 (packed b32 writes) ----
    {
        int r = tid >> 4, sub = tid & 15;         // token r, k-chunk sub: k = sub*12 + i
        float vals[12];
        float sum = 0.f, sq = 0.f;
#pragma unroll
        for (int i = 0; i < 12; i++) {
            int k = sub * 12 + i;
            float val = 0.f;
            if (k < 147) {
                int c = k % 3, pp = k / 3, p1 = pp / 7, p2 = pp % 7;
                val = xs[c * 1568 + p1 * 224 + r * 7 + p2];
            }
            vals[i] = val;
            sum += val; sq += val * val;
        }
#pragma unroll
        for (int m = 1; m < 16; m <<= 1) {
            sum += __shfl_xor(sum, m);
            sq  += __shfl_xor(sq, m);
        }
        float mu = sum * (1.0f / 147.0f);
        float rstd = rsqrtf(sq * (1.0f / 147.0f) - mu * mu + 1e-5f);
        float amax = 0.f;
#pragma unroll
        for (int i = 0; i < 12; i++) {
            int k = sub * 12 + i;
            if (k < 147) {
                float v = (vals[i] - mu) * rstd * g1[k] + b1[k];
                vals[i] = v;
                amax = fmaxf(amax, fabsf(v));
            }
        }
#pragma unroll
        for (int m = 1; m < 16; m <<= 1) amax = fmaxf(amax, __shfl_xor(amax, m));
        float mx = fmaxf(amax, 1e-5f);
        float sx = 127.0f / mx;
        uint32_t w0 = 0, w1 = 0, w2 = 0;
#pragma unroll
        for (int i = 0; i < 12; i++) {
            int k = sub * 12 + i;
            float qv = 0.f;
            if (k < 147) qv = fminf(fmaxf(rintf(vals[i] * sx), -128.f), 127.f);
            uint32_t byte = (uint32_t)((int)qv & 0xFF);
            if (i < 4)      w0 |= byte << (8 * i);
            else if (i < 8) w1 |= byte << (8 * (i - 4));
            else            w2 |= byte << (8 * (i - 8));
        }
        int wb = (r * 208 + sub * 12) >> 2;       // 208-byte row stride (13 x 16B)
        A8w[wb] = w0; A8w[wb + 1] = w1; A8w[wb + 2] = w2;
        if (sub == 0) sxl[r] = mx * (1.0f / 127.0f);
    }
    __syncthreads();

    // ---- phase 2: i8 GEMM, B direct from L2, rolled kk-loop, fenced halves ----
    i32x4 acc[16];
#pragma unroll
    for (int i = 0; i < 16; i++) acc[i] = (i32x4)0;

    const i32x4* Wq4 = (const i32x4*)Wq;
    int arow = wm * 16 + l15;                     // token row 0..31
    int bidx = wn * 128 + l15;                    // B col within half

#pragma unroll 1
    for (int kk = 0; kk < 3; kk++) {
        i32x4 a = A4[arow * 13 + kk * 4 + lg];
        {   // half 0: cols [0,512)
            i32x4 bf[8];
#pragma unroll
            for (int n = 0; n < 8; n++)
                bf[n] = Wq4[(kk * 4 + lg) * 1024 + bidx + n * 16];
#pragma unroll
            for (int n = 0; n < 8; n++)
                acc[n] = __builtin_amdgcn_mfma_i32_16x16x64_i8(a, bf[n], acc[n], 0, 0, 0);
        }
        __builtin_amdgcn_sched_barrier(0);
        {   // half 1: cols [512,1024)
            i32x4 bf[8];
#pragma unroll
            for (int n = 0; n < 8; n++)
                bf[n] = Wq4[(kk * 4 + lg) * 1024 + 512 + bidx + n * 16];
#pragma unroll
            for (int n = 0; n < 8; n++)
                acc[8 + n] = __builtin_amdgcn_mfma_i32_16x16x64_i8(a, bf[n], acc[8 + n], 0, 0, 0);
        }
        __builtin_amdgcn_sched_barrier(0);
    }

    // ---- phase 3: epilogue — dequant + bias, LN2 over 1024 cols, + posemb ----
    float inv_sw = swbuf[0];
    float sc[4];
    int rloc[4];
#pragma unroll
    for (int rr = 0; rr < 4; rr++) {
        rloc[rr] = wm * 16 + lg * 4 + rr;
        sc[rr] = sxl[rloc[rr]] * inv_sw;
    }
    float s[4] = {0.f, 0.f, 0.f, 0.f}, q[4] = {0.f, 0.f, 0.f, 0.f};
#pragma unroll
    for (int h = 0; h < 2; h++)
#pragma unroll
    for (int n = 0; n < 8; n++) {
        const int idx = h * 8 + n;
        int col = h * 512 + wn * 128 + n * 16 + l15;
        float bp = bproj[col];
#pragma unroll
        for (int rr = 0; rr < 4; rr++) {
            float v = (float)acc[idx][rr] * sc[rr] + bp;
            acc[idx][rr] = __float_as_int(v);     // bit-cast in place, no extra regs
            s[rr] += v; q[rr] += v * v;
        }
    }
#pragma unroll
    for (int m = 1; m < 16; m <<= 1) {
#pragma unroll
        for (int rr = 0; rr < 4; rr++) {
            s[rr] += __shfl_xor(s[rr], m);
            q[rr] += __shfl_xor(q[rr], m);
        }
    }
    if (l15 == 0) {
#pragma unroll
        for (int rr = 0; rr < 4; rr++) {
            stats[(rloc[rr] * 4 + wn) * 2 + 0] = s[rr];
            stats[(rloc[rr] * 4 + wn) * 2 + 1] = q[rr];
        }
    }
    __syncthreads();

    float mean[4], rstd2[4];
#pragma unroll
    for (int rr = 0; rr < 4; rr++) {
        float st2 = 0.f, qt = 0.f;
#pragma unroll
        for (int w = 0; w < 4; w++) {
            st2 += stats[(rloc[rr] * 4 + w) * 2 + 0];
            qt  += stats[(rloc[rr] * 4 + w) * 2 + 1];
        }
        float mu = st2 * (1.0f / 1024.0f);
        mean[rr] = mu;
        rstd2[rr] = rsqrtf(qt * (1.0f / 1024.0f) - mu * mu + 1e-5f);
    }

    // col < 512: pe = pe2[xg][col], xg = rloc (since gh*32 ≡ 0 mod 32)
#pragma unroll
    for (int n = 0; n < 8; n++) {
        int col = wn * 128 + n * 16 + l15;
        float gg = g2[col], bb = b2[col];
#pragma unroll
        for (int rr = 0; rr < 4; rr++) {
            int row = rowbase + rloc[rr];
            float v = __int_as_float(acc[n][rr]);
            float o = (v - mean[rr]) * rstd2[rr] * gg + bb + pe2[rloc[rr] * 512 + col];
            out[(size_t)row * 1024 + col] = o;
        }
    }
    // col >= 512: pe = pe2[yg][col-512], yg = gh (row-uniform)
#pragma unroll
    for (int n = 0; n < 8; n++) {
        int colp = wn * 128 + n * 16 + l15;       // col - 512
        int col = 512 + colp;
        float gg = g2[col], bb = b2[col];
        float pv = pe2[gh * 512 + colp];
#pragma unroll
        for (int rr = 0; rr < 4; rr++) {
            int row = rowbase + rloc[rr];
            float v = __int_as_float(acc[8 + n][rr]);
            float o = (v - mean[rr]) * rstd2[rr] * gg + bb + pv;
            out[(size_t)row * 1024 + col] = o;
        }
    }
}

extern "C" void kernel_launch(void* const* d_in, const int* in_sizes, int n_in,
                              void* d_out, int out_size, void* d_ws, size_t ws_size,
                              hipStream_t stream) {
    const float* x     = (const float*)d_in[0];
    const float* ln1_g = (const float*)d_in[1];
    const float* ln1_b = (const float*)d_in[2];
    const float* W     = (const float*)d_in[3];
    const float* bproj = (const float*)d_in[4];
    const float* ln2_g = (const float*)d_in[5];
    const float* ln2_b = (const float*)d_in[6];
    float* out = (float*)d_out;

    // workspace layout
    char* ws = (char*)d_ws;
    float*       pe2   = (float*)ws;                           // 65,536 B
    signed char* Wq    = (signed char*)(ws + 65536u);          // 196,608 B
    float*       part  = (float*)(ws + 65536u + 196608u);      // 147 floats
    float*       swbuf = part + 160;

    pe_gen<<<64, 256, 0, stream>>>(pe2);
    wabs<<<147, 256, 0, stream>>>(W, part);
    wquant<<<768, 256, 0, stream>>>(W, part, swbuf, Wq);
    fused<<<2048, 512, 26624, stream>>>(x, ln1_g, ln1_b, Wq, swbuf, bproj,
                                        ln2_g, ln2_b, pe2, out);
}

// Round 6
// 134.808 us; speedup vs baseline: 1.3765x; 1.3765x over previous
//
#include <hip/hip_runtime.h>
#include <hip/hip_bf16.h>
#include <stdint.h>

// Problem constants
#define BATCH 64
#define CH 3
#define HW 224
#define PP 7
#define GHW 32           // 32x32 patches
#define PD 147           // 7*7*3
#define DIM 1024
#define NTOK 65536       // 64 * 1024 tokens

typedef int   i32x4 __attribute__((ext_vector_type(4)));
typedef float f32x4v __attribute__((ext_vector_type(4)));

// ---------------- positional embedding table pe2[32][512] ----------------
// pe2[g][c] = sin(g*omega[c]) for c<256 ; cos(g*omega[c-256]) for c>=256
// out col<512  (x-quads): pe = pe2[xg][col],      xg = token%32
// out col>=512 (y-quads): pe = pe2[yg][col-512],  yg = gh
__global__ void pe_gen(float* __restrict__ pe2) {
    int id = blockIdx.x * 256 + threadIdx.x;      // < 16384 = 32*512
    int g = id >> 9, c = id & 511;
    int k = c & 255;
    float omega = exp2f(-13.287712379549449f * (float)k * (1.0f / 255.0f));
    float arg = (float)g * omega;
    pe2[id] = (c < 256) ? sinf(arg) : cosf(arg);
}

// ---------------- mean|W| partial sums (deterministic) ----------------
__global__ void wabs(const float* __restrict__ W, float* __restrict__ part) {
    __shared__ float red[256];
    int t = threadIdx.x;
    int base = blockIdx.x * 1024;                 // 147 blocks * 1024 = 150528
    float s = fabsf(W[base + t]) + fabsf(W[base + t + 256]) +
              fabsf(W[base + t + 512]) + fabsf(W[base + t + 768]);
    red[t] = s;
    __syncthreads();
    for (int off = 128; off > 0; off >>= 1) {
        if (t < off) red[t] += red[t + off];
        __syncthreads();
    }
    if (t == 0) part[blockIdx.x] = red[0];
}

// ---------------- ternary weight quant -> int8, MFMA B layout ----------------
// Wq layout: [c = k>>4 (12)][d(1024)][j = k&15] int8, k padded to 192. 192 KB total.
__global__ void wquant(const float* __restrict__ W, const float* __restrict__ part,
                       float* __restrict__ swbuf, signed char* __restrict__ Wq) {
    __shared__ float red[256];
    int tid = threadIdx.x;
    red[tid] = (tid < 147) ? part[tid] : 0.f;
    __syncthreads();
    for (int off = 128; off > 0; off >>= 1) {
        if (tid < off) red[tid] += red[tid + off];
        __syncthreads();
    }
    float m = fmaxf(red[0] * (1.0f / 150528.0f), 1e-5f);
    float sw = 1.0f / m;
    if (blockIdx.x == 0 && tid == 0) swbuf[0] = m;   // dequant scale for gemm

    int e = blockIdx.x * 256 + tid;               // < 196608 = 1024*192
    int d = e / 192, k = e % 192;
    float t = 0.f;
    if (k < 147) {
        t = rintf(W[d * 147 + k] * sw);
        t = fminf(fmaxf(t, -1.f), 1.f);
    }
    Wq[(((k >> 4) << 10) | d) * 16 + (k & 15)] = (signed char)(int)t;
}

// ---------------- fused patchify + LN1 + int8 quant + i8 GEMM + LN2 + posemb ----------
// grid: 4096 blocks, XCD-swizzled gh-major: lblk = gh*128 + b*2 + half.
// Block = 16 tokens x 1024 cols, 512 threads = 8 waves (wn 0..7), wave tile 16x128:
// acc = 8 i32x4 = 32 regs (HALVED vs r5 -> no spills at the 128-reg budget).
// B direct from L2-resident Wq: the 8 wn-slices partition the cols, so per-block
// B traffic = 192 KB either way; no LDS staging, no extra barriers.
// LDS (13824 B):
//   xs   [0,     9408)  : x-stage, [c(3)][p1(7)][112] f32
//   A8   [9408, 12736)  : quantized A int8, [row(16)][208]  (192 used, 13x16B stride)
//   stats[12736, 13760) : [rloc(16)][wn(8)][{sum,sq}] f32
//   sxl  [13760, 13824) : per-token dequant scale f32
__global__ __launch_bounds__(512, 4) void fused(
    const float* __restrict__ x, const float* __restrict__ g1,
    const float* __restrict__ b1, const signed char* __restrict__ Wq,
    const float* __restrict__ swbuf, const float* __restrict__ bproj,
    const float* __restrict__ g2, const float* __restrict__ b2,
    const float* __restrict__ pe2, float* __restrict__ out) {
    extern __shared__ char lds[];
    float*        xs    = (float*)lds;
    uint32_t*     A8w   = (uint32_t*)(lds + 9408);
    const i32x4*  A4    = (const i32x4*)(lds + 9408);
    float*        stats = (float*)(lds + 12736);
    float*        sxl   = (float*)(lds + 13760);

    int tid = threadIdx.x;
    int wave = tid >> 6, lane = tid & 63;
    int wn = wave;                                // col slice [wn*128, wn*128+128)
    int l15 = lane & 15, lg = lane >> 4;

    // XCD-swizzled, gh-major: XCD x owns lblk [x*512, x*512+512) -> gh in [x*4, x*4+4)
    int lblk = (blockIdx.x & 7) * 512 + (blockIdx.x >> 3);
    int gh = lblk >> 7;
    int rem = lblk & 127;
    int b = rem >> 1, half = rem & 1;
    int rowbase = b * 1024 + gh * 32 + half * 16; // output token base

    // ---- phase 0: coalesced x stage (3 ch x 7 rows x 112 floats, as float4) ----
    const f32x4v* x4 = (const f32x4v*)x;
    int base4 = b * 37632 + gh * 392 + half * 28;
    f32x4v* xs4 = (f32x4v*)xs;
#pragma unroll
    for (int it = 0; it < 2; it++) {
        int j = tid + it * 512;
        if (j < 588) {
            int c = j / 196, rem2 = j - c * 196;
            int p1 = rem2 / 28, i4 = rem2 - p1 * 28;
            xs4[j] = x4[base4 + c * 12544 + p1 * 56 + i4];
        }
    }
    __syncthreads();

    // ---- phase 1: LN1 + per-token absmax int8 fake-quant -> A8 (256 threads) ----
    if (tid < 256) {
        int r = tid >> 4, sub = tid & 15;         // token r (0..15), k = sub*12 + i
        float vals[12];
        float sum = 0.f, sq = 0.f;
#pragma unroll
        for (int i = 0; i < 12; i++) {
            int k = sub * 12 + i;
            float val = 0.f;
            if (k < 147) {
                int c = k % 3, pp = k / 3, p1 = pp / 7, p2 = pp % 7;
                val = xs[c * 784 + p1 * 112 + r * 7 + p2];
            }
            vals[i] = val;
            sum += val; sq += val * val;
        }
#pragma unroll
        for (int m = 1; m < 16; m <<= 1) {
            sum += __shfl_xor(sum, m);
            sq  += __shfl_xor(sq, m);
        }
        float mu = sum * (1.0f / 147.0f);
        float rstd = rsqrtf(sq * (1.0f / 147.0f) - mu * mu + 1e-5f);
        float amax = 0.f;
#pragma unroll
        for (int i = 0; i < 12; i++) {
            int k = sub * 12 + i;
            if (k < 147) {
                float v = (vals[i] - mu) * rstd * g1[k] + b1[k];
                vals[i] = v;
                amax = fmaxf(amax, fabsf(v));
            }
        }
#pragma unroll
        for (int m = 1; m < 16; m <<= 1) amax = fmaxf(amax, __shfl_xor(amax, m));
        float mx = fmaxf(amax, 1e-5f);
        float sx = 127.0f / mx;
        uint32_t w0 = 0, w1 = 0, w2 = 0;
#pragma unroll
        for (int i = 0; i < 12; i++) {
            int k = sub * 12 + i;
            float qv = 0.f;
            if (k < 147) qv = fminf(fmaxf(rintf(vals[i] * sx), -128.f), 127.f);
            uint32_t byte = (uint32_t)((int)qv & 0xFF);
            if (i < 4)      w0 |= byte << (8 * i);
            else if (i < 8) w1 |= byte << (8 * (i - 4));
            else            w2 |= byte << (8 * (i - 8));
        }
        int wb = r * 52 + sub * 3;                // (r*208 + sub*12)/4
        A8w[wb] = w0; A8w[wb + 1] = w1; A8w[wb + 2] = w2;
        if (sub == 0) sxl[r] = mx * (1.0f / 127.0f);
    }
    __syncthreads();

    // ---- phase 2: i8 GEMM, B direct from L2, rolled kk loop (no spills) ----
    i32x4 acc[8];
#pragma unroll
    for (int i = 0; i < 8; i++) acc[i] = (i32x4)0;

    const i32x4* Wq4 = (const i32x4*)Wq;
    int bcol = wn * 128 + l15;

#pragma unroll 1
    for (int kk = 0; kk < 3; kk++) {
        i32x4 a = A4[l15 * 13 + kk * 4 + lg];
        i32x4 bf[8];
#pragma unroll
        for (int n = 0; n < 8; n++)
            bf[n] = Wq4[(kk * 4 + lg) * 1024 + bcol + n * 16];
#pragma unroll
        for (int n = 0; n < 8; n++)
            acc[n] = __builtin_amdgcn_mfma_i32_16x16x64_i8(a, bf[n], acc[n], 0, 0, 0);
    }

    // ---- phase 3: epilogue — dequant + bias, LN2 over 1024 cols, + posemb ----
    float inv_sw = swbuf[0];
    float sc[4];
    int rloc[4];
#pragma unroll
    for (int rr = 0; rr < 4; rr++) {
        rloc[rr] = lg * 4 + rr;                   // row within the 16-token block
        sc[rr] = sxl[rloc[rr]] * inv_sw;
    }
    float s[4] = {0.f, 0.f, 0.f, 0.f}, q[4] = {0.f, 0.f, 0.f, 0.f};
#pragma unroll
    for (int n = 0; n < 8; n++) {
        int col = wn * 128 + n * 16 + l15;
        float bp = bproj[col];
#pragma unroll
        for (int rr = 0; rr < 4; rr++) {
            float v = (float)acc[n][rr] * sc[rr] + bp;
            acc[n][rr] = __float_as_int(v);       // bit-cast in place, no extra regs
            s[rr] += v; q[rr] += v * v;
        }
    }
#pragma unroll
    for (int m = 1; m < 16; m <<= 1) {
#pragma unroll
        for (int rr = 0; rr < 4; rr++) {
            s[rr] += __shfl_xor(s[rr], m);
            q[rr] += __shfl_xor(q[rr], m);
        }
    }
    if (l15 == 0) {
#pragma unroll
        for (int rr = 0; rr < 4; rr++) {
            stats[(rloc[rr] * 8 + wn) * 2 + 0] = s[rr];
            stats[(rloc[rr] * 8 + wn) * 2 + 1] = q[rr];
        }
    }
    __syncthreads();

    float mean[4], rstd2[4];
#pragma unroll
    for (int rr = 0; rr < 4; rr++) {
        float st2 = 0.f, qt = 0.f;
#pragma unroll
        for (int w = 0; w < 8; w++) {
            st2 += stats[(rloc[rr] * 8 + w) * 2 + 0];
            qt  += stats[(rloc[rr] * 8 + w) * 2 + 1];
        }
        float mu = st2 * (1.0f / 1024.0f);
        mean[rr] = mu;
        rstd2[rr] = rsqrtf(qt * (1.0f / 1024.0f) - mu * mu + 1e-5f);
    }

    if (wn < 4) {
        // cols [0,512): x-quads, pe row = token%32 = half*16 + rloc
#pragma unroll
        for (int n = 0; n < 8; n++) {
            int col = wn * 128 + n * 16 + l15;
            float gg = g2[col], bb = b2[col];
#pragma unroll
            for (int rr = 0; rr < 4; rr++) {
                int row = rowbase + rloc[rr];
                float v = __int_as_float(acc[n][rr]);
                float o = (v - mean[rr]) * rstd2[rr] * gg + bb
                          + pe2[(half * 16 + rloc[rr]) * 512 + col];
                out[(size_t)row * 1024 + col] = o;
            }
        }
    } else {
        // cols [512,1024): y-quads, pe row = gh (row-uniform)
#pragma unroll
        for (int n = 0; n < 8; n++) {
            int col = wn * 128 + n * 16 + l15;    // 512..1023
            float gg = g2[col], bb = b2[col];
            float pv = pe2[gh * 512 + (col - 512)];
#pragma unroll
            for (int rr = 0; rr < 4; rr++) {
                int row = rowbase + rloc[rr];
                float v = __int_as_float(acc[n][rr]);
                float o = (v - mean[rr]) * rstd2[rr] * gg + bb + pv;
                out[(size_t)row * 1024 + col] = o;
            }
        }
    }
}

extern "C" void kernel_launch(void* const* d_in, const int* in_sizes, int n_in,
                              void* d_out, int out_size, void* d_ws, size_t ws_size,
                              hipStream_t stream) {
    const float* x     = (const float*)d_in[0];
    const float* ln1_g = (const float*)d_in[1];
    const float* ln1_b = (const float*)d_in[2];
    const float* W     = (const float*)d_in[3];
    const float* bproj = (const float*)d_in[4];
    const float* ln2_g = (const float*)d_in[5];
    const float* ln2_b = (const float*)d_in[6];
    float* out = (float*)d_out;

    // workspace layout
    char* ws = (char*)d_ws;
    float*       pe2   = (float*)ws;                           // 65,536 B
    signed char* Wq    = (signed char*)(ws + 65536u);          // 196,608 B
    float*       part  = (float*)(ws + 65536u + 196608u);      // 147 floats
    float*       swbuf = part + 160;

    pe_gen<<<64, 256, 0, stream>>>(pe2);
    wabs<<<147, 256, 0, stream>>>(W, part);
    wquant<<<768, 256, 0, stream>>>(W, part, swbuf, Wq);
    fused<<<4096, 512, 13824, stream>>>(x, ln1_g, ln1_b, Wq, swbuf, bproj,
                                        ln2_g, ln2_b, pe2, out);
}

// Round 7
// 128.985 us; speedup vs baseline: 1.4387x; 1.0451x over previous
//
#include <hip/hip_runtime.h>
#include <hip/hip_bf16.h>
#include <stdint.h>

// Problem constants
#define BATCH 64
#define CH 3
#define HW 224
#define PP 7
#define GHW 32           // 32x32 patches
#define PD 147           // 7*7*3
#define DIM 1024
#define NTOK 65536       // 64 * 1024 tokens

typedef int   i32x4 __attribute__((ext_vector_type(4)));
typedef float f32x4v __attribute__((ext_vector_type(4)));

// ---------------- prelude 1: mean|W| partials + pe table, one launch ----------------
// blocks [0,147): wabs partial sums ; blocks [147,211): pe2[32][512] table
// pe2[g][c] = sin(g*omega[c]) for c<256 ; cos(g*omega[c-256]) for c>=256
// out col<512  (x-quads): pe = pe2[xg][col],      xg = token%32
// out col>=512 (y-quads): pe = pe2[yg][col-512],  yg = gh
__global__ void prep1(const float* __restrict__ W, float* __restrict__ part,
                      float* __restrict__ pe2) {
    int tid = threadIdx.x;
    if (blockIdx.x < 147) {
        __shared__ float red[256];
        int base = blockIdx.x * 1024;             // 147 blocks * 1024 = 150528
        float s = fabsf(W[base + tid]) + fabsf(W[base + tid + 256]) +
                  fabsf(W[base + tid + 512]) + fabsf(W[base + tid + 768]);
        red[tid] = s;
        __syncthreads();
        for (int off = 128; off > 0; off >>= 1) {
            if (tid < off) red[tid] += red[tid + off];
            __syncthreads();
        }
        if (tid == 0) part[blockIdx.x] = red[0];
    } else {
        int id = (blockIdx.x - 147) * 256 + tid;  // < 16384 = 32*512
        int g = id >> 9, c = id & 511;
        int k = c & 255;
        float omega = exp2f(-13.287712379549449f * (float)k * (1.0f / 255.0f));
        float arg = (float)g * omega;
        pe2[id] = (c < 256) ? sinf(arg) : cosf(arg);
    }
}

// ---------------- ternary weight quant -> int8, MFMA fragment layout ----------------
// Wq layout: [c = k>>4 (12)][d(1024)][j = k&15] int8, k padded to 192. 192 KB total.
__global__ void wquant(const float* __restrict__ W, const float* __restrict__ part,
                       float* __restrict__ swbuf, signed char* __restrict__ Wq) {
    __shared__ float red[256];
    int tid = threadIdx.x;
    red[tid] = (tid < 147) ? part[tid] : 0.f;
    __syncthreads();
    for (int off = 128; off > 0; off >>= 1) {
        if (tid < off) red[tid] += red[tid + off];
        __syncthreads();
    }
    float m = fmaxf(red[0] * (1.0f / 150528.0f), 1e-5f);
    float sw = 1.0f / m;
    if (blockIdx.x == 0 && tid == 0) swbuf[0] = m;   // dequant scale for gemm

    int e = blockIdx.x * 256 + tid;               // < 196608 = 1024*192
    int d = e / 192, k = e % 192;
    float t = 0.f;
    if (k < 147) {
        t = rintf(W[d * 147 + k] * sw);
        t = fminf(fmaxf(t, -1.f), 1.f);
    }
    Wq[(((k >> 4) << 10) | d) * 16 + (k & 15)] = (signed char)(int)t;
}

// ---------------- fused patchify + LN1 + int8 quant + i8 GEMM + LN2 + posemb ----------
// grid: 4096 blocks, XCD-swizzled gh-major. Block = 16 tokens x 1024 cols.
// 512 threads = 8 waves (wn 0..7), wave tile 16 tokens x 128 cols, acc = 8 i32x4.
// OPERAND-SWAPPED MFMA: D = mfma(W_frag, Act_frag) so lane&15 = token and
// lg*4+rr = 4 CONSECUTIVE output cols -> float4 epilogue loads AND stores.
// B direct from L2-resident Wq (192 KB/XCD); rolled kk loop keeps regs < 128 (no spill).
// LDS (13824 B):
//   xs   [0,     9408)  : x-stage, [c(3)][p1(7)][112] f32
//   A8   [9408, 12736)  : quantized A int8, [row(16)][208]  (192 used, 13x16B stride)
//   stats[12736, 13760) : [token(16)][wn(8)][{sum,sq}] f32 (256 used)
//   sxl  [13760, 13824) : per-token dequant scale f32
__global__ __launch_bounds__(512, 4) void fused(
    const float* __restrict__ x, const float* __restrict__ g1,
    const float* __restrict__ b1, const signed char* __restrict__ Wq,
    const float* __restrict__ swbuf, const float* __restrict__ bproj,
    const float* __restrict__ g2, const float* __restrict__ b2,
    const float* __restrict__ pe2, float* __restrict__ out) {
    extern __shared__ char lds[];
    float*        xs    = (float*)lds;
    uint32_t*     A8w   = (uint32_t*)(lds + 9408);
    const i32x4*  A4    = (const i32x4*)(lds + 9408);
    float*        stats = (float*)(lds + 12736);
    float*        sxl   = (float*)(lds + 13760);

    int tid = threadIdx.x;
    int wave = tid >> 6, lane = tid & 63;
    int wn = wave;                                // col slice [wn*128, wn*128+128)
    int l15 = lane & 15, lg = lane >> 4;

    // XCD-swizzled, gh-major: XCD x owns lblk [x*512, x*512+512) -> gh in [x*4, x*4+4)
    int lblk = (blockIdx.x & 7) * 512 + (blockIdx.x >> 3);
    int gh = lblk >> 7;
    int rem = lblk & 127;
    int b = rem >> 1, half = rem & 1;
    int rowbase = b * 1024 + gh * 32 + half * 16; // output token base

    // ---- phase 0: coalesced x stage (3 ch x 7 rows x 112 floats, as float4) ----
    const f32x4v* x4 = (const f32x4v*)x;
    int base4 = b * 37632 + gh * 392 + half * 28;
    f32x4v* xs4 = (f32x4v*)xs;
#pragma unroll
    for (int it = 0; it < 2; it++) {
        int j = tid + it * 512;
        if (j < 588) {
            int c = j / 196, rem2 = j - c * 196;
            int p1 = rem2 / 28, i4 = rem2 - p1 * 28;
            xs4[j] = x4[base4 + c * 12544 + p1 * 56 + i4];
        }
    }
    __syncthreads();

    // ---- phase 1: LN1 + per-token absmax int8 fake-quant -> A8 (256 threads) ----
    if (tid < 256) {
        int r = tid >> 4, sub = tid & 15;         // token r (0..15), k = sub*12 + i
        float vals[12];
        float sum = 0.f, sq = 0.f;
#pragma unroll
        for (int i = 0; i < 12; i++) {
            int k = sub * 12 + i;
            float val = 0.f;
            if (k < 147) {
                int c = k % 3, pp = k / 3, p1 = pp / 7, p2 = pp % 7;
                val = xs[c * 784 + p1 * 112 + r * 7 + p2];
            }
            vals[i] = val;
            sum += val; sq += val * val;
        }
#pragma unroll
        for (int m = 1; m < 16; m <<= 1) {
            sum += __shfl_xor(sum, m);
            sq  += __shfl_xor(sq, m);
        }
        float mu = sum * (1.0f / 147.0f);
        float rstd = rsqrtf(sq * (1.0f / 147.0f) - mu * mu + 1e-5f);
        float amax = 0.f;
#pragma unroll
        for (int i = 0; i < 12; i++) {
            int k = sub * 12 + i;
            if (k < 147) {
                float v = (vals[i] - mu) * rstd * g1[k] + b1[k];
                vals[i] = v;
                amax = fmaxf(amax, fabsf(v));
            }
        }
#pragma unroll
        for (int m = 1; m < 16; m <<= 1) amax = fmaxf(amax, __shfl_xor(amax, m));
        float mx = fmaxf(amax, 1e-5f);
        float sx = 127.0f / mx;
        uint32_t w0 = 0, w1 = 0, w2 = 0;
#pragma unroll
        for (int i = 0; i < 12; i++) {
            int k = sub * 12 + i;
            float qv = 0.f;
            if (k < 147) qv = fminf(fmaxf(rintf(vals[i] * sx), -128.f), 127.f);
            uint32_t byte = (uint32_t)((int)qv & 0xFF);
            if (i < 4)      w0 |= byte << (8 * i);
            else if (i < 8) w1 |= byte << (8 * (i - 4));
            else            w2 |= byte << (8 * (i - 8));
        }
        int wb = r * 52 + sub * 3;                // (r*208 + sub*12)/4
        A8w[wb] = w0; A8w[wb + 1] = w1; A8w[wb + 2] = w2;
        if (sub == 0) sxl[r] = mx * (1.0f / 127.0f);
    }
    __syncthreads();

    // ---- phase 2: i8 GEMM (operand-swapped), B direct from L2, rolled kk loop ----
    i32x4 acc[8];
#pragma unroll
    for (int i = 0; i < 8; i++) acc[i] = (i32x4)0;

    const i32x4* Wq4 = (const i32x4*)Wq;
    int bcol = wn * 128 + l15;

#pragma unroll 1
    for (int kk = 0; kk < 3; kk++) {
        i32x4 a = A4[l15 * 13 + kk * 4 + lg];     // token = l15, k-chunk = lg
        i32x4 bf[8];
#pragma unroll
        for (int n = 0; n < 8; n++)
            bf[n] = Wq4[(kk * 4 + lg) * 1024 + bcol + n * 16];
#pragma unroll
        for (int n = 0; n < 8; n++)               // D[dcol][token]: operands swapped
            acc[n] = __builtin_amdgcn_mfma_i32_16x16x64_i8(bf[n], a, acc[n], 0, 0, 0);
    }

    // ---- phase 3: epilogue — dequant + bias, LN2 over 1024 cols, + posemb ----
    // thread owns: token = l15 (one row), cols = wn*128 + n*16 + lg*4 + rr (float4!)
    float inv_sw = swbuf[0];
    int token = l15;
    float sc = sxl[token] * inv_sw;
    int colbase = wn * 128 + lg * 4;

    float s = 0.f, q = 0.f;
#pragma unroll
    for (int n = 0; n < 8; n++) {
        int col = colbase + n * 16;
        f32x4v bp = *(const f32x4v*)(bproj + col);
#pragma unroll
        for (int rr = 0; rr < 4; rr++) {
            float v = (float)acc[n][rr] * sc + bp[rr];
            acc[n][rr] = __float_as_int(v);       // bit-cast in place, no extra regs
            s += v; q += v * v;
        }
    }
    // reduce across the 4 lg groups (lanes token, token+16, token+32, token+48)
    s += __shfl_xor(s, 16); s += __shfl_xor(s, 32);
    q += __shfl_xor(q, 16); q += __shfl_xor(q, 32);
    if (lg == 0) {
        stats[(token * 8 + wn) * 2 + 0] = s;
        stats[(token * 8 + wn) * 2 + 1] = q;
    }
    __syncthreads();

    float st = 0.f, qt = 0.f;
#pragma unroll
    for (int w = 0; w < 8; w++) {
        st += stats[(token * 8 + w) * 2 + 0];
        qt += stats[(token * 8 + w) * 2 + 1];
    }
    float mean = st * (1.0f / 1024.0f);
    float rstd = rsqrtf(qt * (1.0f / 1024.0f) - mean * mean + 1e-5f);

    float* orow = out + (size_t)(rowbase + token) * 1024;
    if (wn < 4) {
        // cols [0,512): x-quads, pe row = token%32 = half*16 + token
        const float* perow = pe2 + (half * 16 + token) * 512;
#pragma unroll
        for (int n = 0; n < 8; n++) {
            int col = colbase + n * 16;
            f32x4v gg = *(const f32x4v*)(g2 + col);
            f32x4v bb = *(const f32x4v*)(b2 + col);
            f32x4v pv = *(const f32x4v*)(perow + col);
            f32x4v o;
#pragma unroll
            for (int rr = 0; rr < 4; rr++) {
                float v = __int_as_float(acc[n][rr]);
                o[rr] = (v - mean) * rstd * gg[rr] + bb[rr] + pv[rr];
            }
            __builtin_nontemporal_store(o, (f32x4v*)(orow + col));
        }
    } else {
        // cols [512,1024): y-quads, pe row = gh (token-uniform)
        const float* perow = pe2 + gh * 512 - 512;
#pragma unroll
        for (int n = 0; n < 8; n++) {
            int col = colbase + n * 16;
            f32x4v gg = *(const f32x4v*)(g2 + col);
            f32x4v bb = *(const f32x4v*)(b2 + col);
            f32x4v pv = *(const f32x4v*)(perow + col);
            f32x4v o;
#pragma unroll
            for (int rr = 0; rr < 4; rr++) {
                float v = __int_as_float(acc[n][rr]);
                o[rr] = (v - mean) * rstd * gg[rr] + bb[rr] + pv[rr];
            }
            __builtin_nontemporal_store(o, (f32x4v*)(orow + col));
        }
    }
}

extern "C" void kernel_launch(void* const* d_in, const int* in_sizes, int n_in,
                              void* d_out, int out_size, void* d_ws, size_t ws_size,
                              hipStream_t stream) {
    const float* x     = (const float*)d_in[0];
    const float* ln1_g = (const float*)d_in[1];
    const float* ln1_b = (const float*)d_in[2];
    const float* W     = (const float*)d_in[3];
    const float* bproj = (const float*)d_in[4];
    const float* ln2_g = (const float*)d_in[5];
    const float* ln2_b = (const float*)d_in[6];
    float* out = (float*)d_out;

    // workspace layout
    char* ws = (char*)d_ws;
    float*       pe2   = (float*)ws;                           // 65,536 B
    signed char* Wq    = (signed char*)(ws + 65536u);          // 196,608 B
    float*       part  = (float*)(ws + 65536u + 196608u);      // 147 floats
    float*       swbuf = part + 160;

    prep1<<<211, 256, 0, stream>>>(W, part, pe2);
    wquant<<<768, 256, 0, stream>>>(W, part, swbuf, Wq);
    fused<<<4096, 512, 13824, stream>>>(x, ln1_g, ln1_b, Wq, swbuf, bproj,
                                        ln2_g, ln2_b, pe2, out);
}

// Round 8
// 112.788 us; speedup vs baseline: 1.6453x; 1.1436x over previous
//
#include <hip/hip_runtime.h>
#include <hip/hip_bf16.h>
#include <stdint.h>

// Problem constants
#define BATCH 64
#define CH 3
#define HW 224
#define PP 7
#define GHW 32           // 32x32 patches
#define PD 147           // 7*7*3
#define DIM 1024
#define NTOK 65536       // 64 * 1024 tokens

typedef int   i32x4 __attribute__((ext_vector_type(4)));
typedef float f32x4v __attribute__((ext_vector_type(4)));
typedef float f32x2v __attribute__((ext_vector_type(2)));

// ---------------- prelude 1: mean|W| partials + pe table, one launch ----------------
__global__ void prep1(const float* __restrict__ W, float* __restrict__ part,
                      float* __restrict__ pe2) {
    int tid = threadIdx.x;
    if (blockIdx.x < 147) {
        __shared__ float red[256];
        int base = blockIdx.x * 1024;             // 147 blocks * 1024 = 150528
        float s = fabsf(W[base + tid]) + fabsf(W[base + tid + 256]) +
                  fabsf(W[base + tid + 512]) + fabsf(W[base + tid + 768]);
        red[tid] = s;
        __syncthreads();
        for (int off = 128; off > 0; off >>= 1) {
            if (tid < off) red[tid] += red[tid + off];
            __syncthreads();
        }
        if (tid == 0) part[blockIdx.x] = red[0];
    } else {
        int id = (blockIdx.x - 147) * 256 + tid;  // < 16384 = 32*512
        int g = id >> 9, c = id & 511;
        int k = c & 255;
        float omega = exp2f(-13.287712379549449f * (float)k * (1.0f / 255.0f));
        float arg = (float)g * omega;
        pe2[id] = (c < 256) ? sinf(arg) : cosf(arg);
    }
}

// ---------------- ternary weight quant -> int8, MFMA fragment layout ----------------
// Wq layout: [c = k>>4 (12)][d(1024)][j = k&15] int8, k padded to 192. 192 KB total.
__global__ void wquant(const float* __restrict__ W, const float* __restrict__ part,
                       float* __restrict__ swbuf, signed char* __restrict__ Wq) {
    __shared__ float red[256];
    int tid = threadIdx.x;
    red[tid] = (tid < 147) ? part[tid] : 0.f;
    __syncthreads();
    for (int off = 128; off > 0; off >>= 1) {
        if (tid < off) red[tid] += red[tid + off];
        __syncthreads();
    }
    float m = fmaxf(red[0] * (1.0f / 150528.0f), 1e-5f);
    float sw = 1.0f / m;
    if (blockIdx.x == 0 && tid == 0) swbuf[0] = m;   // dequant scale for gemm

    int e = blockIdx.x * 256 + tid;               // < 196608 = 1024*192
    int d = e / 192, k = e % 192;
    float t = 0.f;
    if (k < 147) {
        t = rintf(W[d * 147 + k] * sw);
        t = fminf(fmaxf(t, -1.f), 1.f);
    }
    Wq[(((k >> 4) << 10) | d) * 16 + (k & 15)] = (signed char)(int)t;
}

// ---------------- fused patchify + LN1 + int8 quant + i8 GEMM + LN2 + posemb ----------
// grid: 4096 blocks, XCD-swizzled gh-major. Block = 16 tokens x 1024 cols.
// 512 threads = 8 waves (wn 0..7), wave tile 16 tokens x 128 cols, acc = 8 i32x4.
// OPERAND-SWAPPED MFMA: lane&15 = token, lg*4+rr = 4 consecutive cols.
// NEW: wave-private LDS-transpose epilogue -> every global store instruction writes
// 4 rows x 256 B fully contiguous (full 128-B lines), fixing the 64 B/row partial-line
// store granularity that capped write BW at ~2.2 TB/s through r7.
// LDS (34816 B):
//   phase 0-2 : xs [0,9408) f32 ; A8 [9408,12736) ; stats [12736,13760) ; sxl [13760,13824)
//   epilogue  : T  [0,34816) = 8 wave-private regions of 272 16B-units (16 rows x 17,
//               stride 17 units -> 8 lanes/quad = conflict-free b128)
__global__ __launch_bounds__(512, 4) void fused(
    const float* __restrict__ x, const float* __restrict__ g1,
    const float* __restrict__ b1, const signed char* __restrict__ Wq,
    const float* __restrict__ swbuf, const float* __restrict__ bproj,
    const float* __restrict__ g2, const float* __restrict__ b2,
    const float* __restrict__ pe2, float* __restrict__ out) {
    extern __shared__ char lds[];
    float*        xs    = (float*)lds;
    uint32_t*     A8w   = (uint32_t*)(lds + 9408);
    const i32x4*  A4    = (const i32x4*)(lds + 9408);
    f32x2v*       stats = (f32x2v*)(lds + 12736); // [wn(8)][token(16)] {sum,sq}
    float*        sxl   = (float*)(lds + 13760);
    f32x4v*       T     = (f32x4v*)lds;           // epilogue transpose buffer

    int tid = threadIdx.x;
    int wave = tid >> 6, lane = tid & 63;
    int wn = wave;                                // col slice [wn*128, wn*128+128)
    int l15 = lane & 15, lg = lane >> 4;

    // XCD-swizzled, gh-major: XCD x owns lblk [x*512, x*512+512) -> gh in [x*4, x*4+4)
    int lblk = (blockIdx.x & 7) * 512 + (blockIdx.x >> 3);
    int gh = lblk >> 7;
    int rem = lblk & 127;
    int b = rem >> 1, half = rem & 1;
    int rowbase = b * 1024 + gh * 32 + half * 16; // output token base

    // ---- phase 0: coalesced x stage (3 ch x 7 rows x 112 floats, as float4) ----
    const f32x4v* x4 = (const f32x4v*)x;
    int base4 = b * 37632 + gh * 392 + half * 28;
    f32x4v* xs4 = (f32x4v*)xs;
#pragma unroll
    for (int it = 0; it < 2; it++) {
        int j = tid + it * 512;
        if (j < 588) {
            int c = j / 196, rem2 = j - c * 196;
            int p1 = rem2 / 28, i4 = rem2 - p1 * 28;
            xs4[j] = x4[base4 + c * 12544 + p1 * 56 + i4];
        }
    }
    __syncthreads();

    // ---- phase 1: LN1 + per-token absmax int8 fake-quant -> A8 (256 threads) ----
    if (tid < 256) {
        int r = tid >> 4, sub = tid & 15;         // token r (0..15), k = sub*12 + i
        float vals[12];
        float sum = 0.f, sq = 0.f;
#pragma unroll
        for (int i = 0; i < 12; i++) {
            int k = sub * 12 + i;
            float val = 0.f;
            if (k < 147) {
                int c = k % 3, pp = k / 3, p1 = pp / 7, p2 = pp % 7;
                val = xs[c * 784 + p1 * 112 + r * 7 + p2];
            }
            vals[i] = val;
            sum += val; sq += val * val;
        }
#pragma unroll
        for (int m = 1; m < 16; m <<= 1) {
            sum += __shfl_xor(sum, m);
            sq  += __shfl_xor(sq, m);
        }
        float mu = sum * (1.0f / 147.0f);
        float rstd = rsqrtf(sq * (1.0f / 147.0f) - mu * mu + 1e-5f);
        float amax = 0.f;
#pragma unroll
        for (int i = 0; i < 12; i++) {
            int k = sub * 12 + i;
            if (k < 147) {
                float v = (vals[i] - mu) * rstd * g1[k] + b1[k];
                vals[i] = v;
                amax = fmaxf(amax, fabsf(v));
            }
        }
#pragma unroll
        for (int m = 1; m < 16; m <<= 1) amax = fmaxf(amax, __shfl_xor(amax, m));
        float mx = fmaxf(amax, 1e-5f);
        float sx = 127.0f / mx;
        uint32_t w0 = 0, w1 = 0, w2 = 0;
#pragma unroll
        for (int i = 0; i < 12; i++) {
            int k = sub * 12 + i;
            float qv = 0.f;
            if (k < 147) qv = fminf(fmaxf(rintf(vals[i] * sx), -128.f), 127.f);
            uint32_t byte = (uint32_t)((int)qv & 0xFF);
            if (i < 4)      w0 |= byte << (8 * i);
            else if (i < 8) w1 |= byte << (8 * (i - 4));
            else            w2 |= byte << (8 * (i - 8));
        }
        int wb = r * 52 + sub * 3;                // (r*208 + sub*12)/4
        A8w[wb] = w0; A8w[wb + 1] = w1; A8w[wb + 2] = w2;
        if (sub == 0) sxl[r] = mx * (1.0f / 127.0f);
    }
    __syncthreads();

    // ---- phase 2: i8 GEMM (operand-swapped), B direct from L2, rolled kk loop ----
    i32x4 acc[8];
#pragma unroll
    for (int i = 0; i < 8; i++) acc[i] = (i32x4)0;

    const i32x4* Wq4 = (const i32x4*)Wq;
    int bcol = wn * 128 + l15;

#pragma unroll 1
    for (int kk = 0; kk < 3; kk++) {
        i32x4 a = A4[l15 * 13 + kk * 4 + lg];     // token = l15, k-chunk = lg
        i32x4 bf[8];
#pragma unroll
        for (int n = 0; n < 8; n++)
            bf[n] = Wq4[(kk * 4 + lg) * 1024 + bcol + n * 16];
#pragma unroll
        for (int n = 0; n < 8; n++)               // D[dcol][token]: operands swapped
            acc[n] = __builtin_amdgcn_mfma_i32_16x16x64_i8(bf[n], a, acc[n], 0, 0, 0);
    }

    // ---- phase 3a: dequant + bias, LN2 stats over 1024 cols ----
    // thread owns: token = l15 (one row), cols = wn*128 + n*16 + lg*4 + rr
    float inv_sw = swbuf[0];
    int token = l15;
    float sc = sxl[token] * inv_sw;
    int colbase = wn * 128 + lg * 4;

    float s = 0.f, q = 0.f;
#pragma unroll
    for (int n = 0; n < 8; n++) {
        int col = colbase + n * 16;
        f32x4v bp = *(const f32x4v*)(bproj + col);
#pragma unroll
        for (int rr = 0; rr < 4; rr++) {
            float v = (float)acc[n][rr] * sc + bp[rr];
            acc[n][rr] = __float_as_int(v);       // bit-cast in place, no extra regs
            s += v; q += v * v;
        }
    }
    s += __shfl_xor(s, 16); s += __shfl_xor(s, 32);
    q += __shfl_xor(q, 16); q += __shfl_xor(q, 32);
    if (lg == 0) {
        f32x2v sv; sv[0] = s; sv[1] = q;
        stats[wn * 16 + token] = sv;              // [wn][token], b64, conflict-free
    }
    __syncthreads();

    float st = 0.f, qt = 0.f;
#pragma unroll
    for (int w = 0; w < 8; w++) {
        f32x2v sv = stats[w * 16 + token];
        st += sv[0]; qt += sv[1];
    }
    float mean = st * (1.0f / 1024.0f);
    float rstd = rsqrtf(qt * (1.0f / 1024.0f) - mean * mean + 1e-5f);
    __syncthreads();   // all stats/sxl reads done before T overwrites the region

    // ---- phase 3b: LN2 apply + posemb, wave-private LDS transpose, full-line stores ----
    // pe rows: cols<512 use pe2[half*16+token]; cols>=512 use pe2[gh] (token-uniform)
    const float* perow = (wn < 4) ? (pe2 + (half * 16 + token) * 512)
                                  : (pe2 + gh * 512 - 512);
    int wbaseu = wave * 272;                      // 272 16B-units per wave region

#pragma unroll
    for (int p = 0; p < 2; p++) {
        // write pass: 4 cols-groups -> LDS (row = token, slot = ni*4+lg, stride 17)
#pragma unroll
        for (int ni = 0; ni < 4; ni++) {
            int n = p * 4 + ni;
            int col = colbase + n * 16;
            f32x4v gg = *(const f32x4v*)(g2 + col);
            f32x4v bb = *(const f32x4v*)(b2 + col);
            f32x4v pv = *(const f32x4v*)(perow + col);
            f32x4v o;
#pragma unroll
            for (int rr = 0; rr < 4; rr++) {
                float v = __int_as_float(acc[n][rr]);
                o[rr] = (v - mean) * rstd * gg[rr] + bb[rr] + pv[rr];
            }
            T[wbaseu + l15 * 17 + ni * 4 + lg] = o;
        }
        // read-back pass: row = j*4+lg, slot = l15 -> 4 rows x 256 B contiguous stores
#pragma unroll
        for (int j = 0; j < 4; j++) {
            f32x4v v = T[wbaseu + (j * 4 + lg) * 17 + l15];
            int row = rowbase + j * 4 + lg;
            int col = wn * 128 + p * 64 + l15 * 4;
            __builtin_nontemporal_store(v, (f32x4v*)(out + (size_t)row * 1024 + col));
        }
    }
}

extern "C" void kernel_launch(void* const* d_in, const int* in_sizes, int n_in,
                              void* d_out, int out_size, void* d_ws, size_t ws_size,
                              hipStream_t stream) {
    const float* x     = (const float*)d_in[0];
    const float* ln1_g = (const float*)d_in[1];
    const float* ln1_b = (const float*)d_in[2];
    const float* W     = (const float*)d_in[3];
    const float* bproj = (const float*)d_in[4];
    const float* ln2_g = (const float*)d_in[5];
    const float* ln2_b = (const float*)d_in[6];
    float* out = (float*)d_out;

    // workspace layout
    char* ws = (char*)d_ws;
    float*       pe2   = (float*)ws;                           // 65,536 B
    signed char* Wq    = (signed char*)(ws + 65536u);          // 196,608 B
    float*       part  = (float*)(ws + 65536u + 196608u);      // 147 floats
    float*       swbuf = part + 160;

    prep1<<<211, 256, 0, stream>>>(W, part, pe2);
    wquant<<<768, 256, 0, stream>>>(W, part, swbuf, Wq);
    fused<<<4096, 512, 34816, stream>>>(x, ln1_g, ln1_b, Wq, swbuf, bproj,
                                        ln2_g, ln2_b, pe2, out);
}